// Round 1
// baseline (59.253 us; speedup 1.0000x reference)
//
#include <hip/hip_runtime.h>

#define NH    52
#define NW    52
#define NA_M  3          // masked anchors
#define NCLS  80
#define TMAX  50
#define PLANE (NH*NW)    // 2704
#define IGN_T 0.6f

__device__ __forceinline__ float softplusf(float x) {
    // stable log(1+exp(x))
    return fmaxf(x, 0.f) + log1pf(expf(-fabsf(x)));
}

__global__ void yolo_zero(float* out) {
    if (threadIdx.x == 0 && blockIdx.x == 0) out[0] = 0.f;
}

__global__ __launch_bounds__(256) void yolo_main(
    const float* __restrict__ inp,   // (32, 255, 52, 52)
    const float* __restrict__ tgt,   // (32, 250)
    float* __restrict__ out)
{
    __shared__ float s_gx[TMAX], s_gy[TMAX], s_gw[TMAX], s_gh[TMAX];
    __shared__ float s_tx[TMAX], s_ty[TMAX], s_tw[TMAX], s_th[TMAX], s_cs[TMAX];
    __shared__ int   s_key[TMAX], s_cls[TMAX], s_vflag[TMAX];
    __shared__ float s_red[4];

    const int tid = threadIdx.x;
    const int ba  = blockIdx.y;      // b*3 + a
    const int b   = ba / 3;
    const int a   = ba % 3;

    // anchors / STRIDE(8): pairs (10,13)(16,30)(33,23)(30,61)(62,45)(59,119)(116,90)(156,198)(373,326)
    const float AW[9] = {1.25f, 2.0f,  4.125f, 3.75f,  7.75f,  7.375f, 14.5f,  19.5f,  46.625f};
    const float AH[9] = {1.625f,3.75f, 2.875f, 7.625f, 5.625f, 14.875f,11.25f, 24.75f, 40.75f};

    // ---------- target preprocessing: threads 0..49, batch b ----------
    float x = 0.f, y = 0.f, w = 0.f, h = 0.f;
    int   clsid = 0;
    if (tid < TMAX) {
        const float* tp = tgt + (size_t)b * (TMAX*5) + tid * 5;
        clsid = (int)tp[0];
        x = tp[1]; y = tp[2]; w = tp[3]; h = tp[4];
        s_vflag[tid] = (x != 0.0f) ? 1 : 0;
    }
    __syncthreads();
    if (tid < TMAX) {
        int valid = 1;
        for (int t2 = 0; t2 <= tid; ++t2) valid &= s_vflag[t2];

        float gx = x*NW, gy = y*NH, gw = w*NW, gh = h*NH;
        int   key = -1;
        float txv = 0.f, tyv = 0.f, twv = 0.f, thv = 0.f, csv = 0.f;
        if (!valid) {
            gx = gy = gw = gh = 0.f;   // yields IoU == 0 vs any pred box
        } else {
            // best of all 9 anchors by wh-IoU (first index wins ties, like argmax)
            float best = -1.f; int bn = 0;
            for (int n = 0; n < 9; ++n) {
                float inter = fminf(gw, AW[n]) * fminf(gh, AH[n]);
                float uni   = gw*gh + AW[n]*AH[n] - inter;
                float r     = inter / uni;
                if (r > best) { best = r; bn = n; }
            }
            if (bn < NA_M) {           // LUT: anchors 0..2 -> selected
                int gi = (int)gx, gj = (int)gy;
                if ((unsigned)gi < NW && (unsigned)gj < NH) {   // scatter mode='drop'
                    key = (bn << 12) | (gj << 6) | gi;
                    txv = gx - (float)gi;
                    tyv = gy - (float)gj;
                    twv = logf(gw / AW[bn]);
                    thv = logf(gh / AH[bn]);
                    csv = 2.f - gw*gh / (float)PLANE;
                }
            }
        }
        s_gx[tid] = gx; s_gy[tid] = gy; s_gw[tid] = gw; s_gh[tid] = gh;
        s_tx[tid] = txv; s_ty[tid] = tyv; s_tw[tid] = twv; s_th[tid] = thv;
        s_cs[tid] = csv; s_key[tid] = key; s_cls[tid] = clsid;
    }
    __syncthreads();

    // ---------- per-cell work ----------
    const int idx = blockIdx.x * blockDim.x + tid;
    float acc = 0.f;
    if (idx < PLANE) {
        const int i = idx % NW;
        const int j = idx / NW;
        const float* base = inp + ((size_t)b * 255 + (size_t)a * 85) * PLANE + idx;
        const float lx    = base[0];
        const float ly    = base[(size_t)1*PLANE];
        const float lw    = base[(size_t)2*PLANE];
        const float lh    = base[(size_t)3*PLANE];
        const float lconf = base[(size_t)4*PLANE];

        const float sx = 1.f / (1.f + expf(-lx));
        const float sy = 1.f / (1.f + expf(-ly));
        const float px = sx + (float)i;
        const float py = sy + (float)j;
        const float pw = expf(lw) * AW[a];
        const float ph = expf(lh) * AH[a];
        const float hw = 0.5f * pw, hh = 0.5f * ph;
        const float parea = pw * ph;

        float cur = 0.f;
        int   hit = -1;                       // last-wins, like sequential scatter
        unsigned long long cmask0 = 0ull, cmask1 = 0ull;
        const int mykey = (a << 12) | (j << 6) | i;

        for (int t = 0; t < TMAX; ++t) {
            const float gx = s_gx[t], gy = s_gy[t], gw = s_gw[t], gh = s_gh[t];
            const float mx = fminf(px - hw, gx - 0.5f*gw);
            const float Mx = fmaxf(px + hw, gx + 0.5f*gw);
            const float my = fminf(py - hh, gy - 0.5f*gh);
            const float My = fmaxf(py + hh, gy + 0.5f*gh);
            const float cw = pw + gw - (Mx - mx);
            const float ch = ph + gh - (My - my);
            const float inter = (cw > 0.f && ch > 0.f) ? cw * ch : 0.f;
            const float uni = parea + gw*gh - inter;
            cur = fmaxf(cur, inter / uni);
            if (s_key[t] == mykey) {
                hit = t;
                const int c = s_cls[t];
                if (c < 64) cmask0 |= (1ull << c);
                else        cmask1 |= (1ull << (c - 64));
            }
        }

        const bool ignored = cur > IGN_T;     // tconf0 == -1 at this cell
        const float tconf = (hit >= 0) ? 1.f : (ignored ? -1.f : 0.f);
        if (tconf != -1.f)
            acc += softplusf(lconf) - tconf * lconf;

        if (hit >= 0) {
            const float cs = s_cs[hit];
            acc += cs * (softplusf(lx) - s_tx[hit] * lx);
            acc += cs * (softplusf(ly) - s_ty[hit] * ly);
            const float dw = lw - s_tw[hit];
            const float dh = lh - s_th[hit];
            acc += 0.5f * cs * dw * dw;
            acc += 0.5f * cs * dh * dh;

            // class loss: only scattered cells participate.
            // Z (tcls zero-slice) applies iff a sel&ign target hit here == hit && ignored.
            const float* cb = base + (size_t)5 * PLANE;
            if (ignored) {
                for (int c = 0; c < NCLS; ++c) {
                    const float l = cb[(size_t)c * PLANE];
                    const bool one = (c < 64) ? ((cmask0 >> c) & 1ull)
                                              : ((cmask1 >> (c - 64)) & 1ull);
                    acc += softplusf(l) - (one ? l : 0.f);
                }
            } else {
                unsigned long long m0 = cmask0, m1 = cmask1;
                while (m0) {
                    const int c = __ffsll((unsigned long long)m0) - 1;
                    m0 &= (m0 - 1);
                    const float l = cb[(size_t)c * PLANE];
                    acc += softplusf(l) - l;
                }
                while (m1) {
                    const int c = __ffsll((unsigned long long)m1) - 1 + 64;
                    m1 &= (m1 - 1);
                    const float l = cb[(size_t)c * PLANE];
                    acc += softplusf(l) - l;
                }
            }
        }
    }

    // ---------- reduction: wave64 shuffle -> LDS -> one atomic per block ----------
    for (int off = 32; off > 0; off >>= 1)
        acc += __shfl_down(acc, off, 64);
    const int wave = tid >> 6;
    const int lane = tid & 63;
    if (lane == 0) s_red[wave] = acc;
    __syncthreads();
    if (tid == 0) {
        float s = s_red[0] + s_red[1] + s_red[2] + s_red[3];
        atomicAdd(out, s);
    }
}

extern "C" void kernel_launch(void* const* d_in, const int* in_sizes, int n_in,
                              void* d_out, int out_size, void* d_ws, size_t ws_size,
                              hipStream_t stream) {
    const float* inp = (const float*)d_in[0];   // (32, 255, 52, 52) f32
    const float* tgt = (const float*)d_in[1];   // (32, 250) f32
    float* out = (float*)d_out;                 // 1 f32

    yolo_zero<<<dim3(1), dim3(64), 0, stream>>>(out);

    dim3 grid((PLANE + 255) / 256, 32 * NA_M);  // 11 x 96
    yolo_main<<<grid, dim3(256), 0, stream>>>(inp, tgt, out);
}

// Round 2
// 33.304 us; speedup vs baseline: 1.7792x; 1.7792x over previous
//
#include <hip/hip_runtime.h>

#define NH    52
#define NW    52
#define NCLS  80
#define TMAX  50
#define PLANE (NH*NW)    // 2704

__device__ __forceinline__ float softplus_fast(float x) {
    // stable log(1+exp(x)) with native exp/log
    return fmaxf(x, 0.f) + __logf(1.f + __expf(-fabsf(x)));
}

__global__ void yolo_zero(float* out) {
    if (threadIdx.x == 0 && blockIdx.x == 0) out[0] = 0.f;
}

__global__ __launch_bounds__(256) void yolo_main(
    const float* __restrict__ inp,   // (32, 255, 52, 52)
    const float* __restrict__ tgt,   // (32, 250)
    float* __restrict__ out)
{
    // s_tab layout: per target t:
    //   [2t]     = {gxl, gxr, gyl, gyr}
    //   [2t+1]   = {0.6*garea, key_bits, cls, 0}
    //   [100+2t] = {tx, ty, tw, th}
    //   [100+2t+1] = {coord_scale, 0, 0, 0}
    __shared__ float4 s_tab[200];
    __shared__ float  s_red[4];

    const int tid = threadIdx.x;
    const int ba  = blockIdx.y;      // b*3 + a
    const int b   = ba / 3;
    const int a   = ba % 3;

    // anchors / STRIDE(8)
    const float AW[9] = {1.25f, 2.0f,  4.125f, 3.75f,  7.75f,  7.375f, 14.5f,  19.5f,  46.625f};
    const float AH[9] = {1.625f,3.75f, 2.875f, 7.625f, 5.625f, 14.875f,11.25f, 24.75f, 40.75f};

    // ---------- target preprocessing: wave 0 only ----------
    if (tid < 64) {
        float cls = 0.f, x = 0.f, y = 0.f, w = 0.f, h = 0.f;
        if (tid < TMAX) {
            const float* tp = tgt + (size_t)b * (TMAX*5) + tid * 5;
            cls = tp[0]; x = tp[1]; y = tp[2]; w = tp[3]; h = tp[4];
        }
        const unsigned long long m = __ballot((tid < TMAX) ? (x != 0.f) : true);
        if (tid < TMAX) {
            const bool valid = ((~m) & ((2ull << tid) - 1ull)) == 0ull;  // cumprod over 0..tid
            float gx = 0.f, gy = 0.f, gw = 0.f, gh = 0.f;
            int   key = -1;
            float txv = 0.f, tyv = 0.f, twv = 0.f, thv = 0.f, csv = 0.f;
            if (valid) {
                gx = x*NW; gy = y*NH; gw = w*NW; gh = h*NH;
                float best = -1.f; int bn = 0;
                #pragma unroll
                for (int n = 0; n < 9; ++n) {
                    const float inter = fminf(gw, AW[n]) * fminf(gh, AH[n]);
                    const float uni   = gw*gh + AW[n]*AH[n] - inter;
                    const float r     = inter / uni;
                    if (r > best) { best = r; bn = n; }
                }
                if (bn < 3) {                         // masked anchors 0..2 selected
                    const int gi = (int)gx, gj = (int)gy;
                    if ((unsigned)gi < NW && (unsigned)gj < NH) {  // scatter mode='drop'
                        key = (bn << 12) | (gj << 6) | gi;
                        txv = gx - (float)gi;
                        tyv = gy - (float)gj;
                        twv = __logf(gw / AW[bn]);
                        thv = __logf(gh / AH[bn]);
                        csv = 2.f - gw*gh * (1.f/(float)PLANE);
                    }
                }
            }
            s_tab[2*tid]       = make_float4(gx - 0.5f*gw, gx + 0.5f*gw, gy - 0.5f*gh, gy + 0.5f*gh);
            s_tab[2*tid+1]     = make_float4(0.6f*gw*gh, __int_as_float(key), cls, 0.f);
            s_tab[100+2*tid]   = make_float4(txv, tyv, twv, thv);
            s_tab[100+2*tid+1] = make_float4(csv, 0.f, 0.f, 0.f);
        }
    }
    __syncthreads();

    // ---------- per-cell work ----------
    const int idx = blockIdx.x * blockDim.x + tid;
    float acc = 0.f;
    if (idx < PLANE) {
        const int i = idx % NW;
        const int j = idx / NW;
        const float* base = inp + ((size_t)b * 255 + (size_t)a * 85) * PLANE + idx;
        const float lx    = base[0];
        const float ly    = base[(size_t)1*PLANE];
        const float lw    = base[(size_t)2*PLANE];
        const float lh    = base[(size_t)3*PLANE];
        const float lconf = base[(size_t)4*PLANE];

        const float sx = __builtin_amdgcn_rcpf(1.f + __expf(-lx));
        const float sy = __builtin_amdgcn_rcpf(1.f + __expf(-ly));
        const float px = sx + (float)i;
        const float py = sy + (float)j;
        const float pw = __expf(lw) * AW[a];
        const float ph = __expf(lh) * AH[a];
        const float pxl = px - 0.5f*pw, pxr = px + 0.5f*pw;
        const float pyl = py - 0.5f*ph, pyr = py + 0.5f*ph;
        const float c06 = 0.6f * (pw * ph);   // 0.6*parea

        bool ignored = false;
        int  hit = -1;                         // last-wins, like sequential scatter
        const int mykey = (a << 12) | (j << 6) | i;

        #pragma unroll 5
        for (int t = 0; t < TMAX; ++t) {
            const float4 A = s_tab[2*t];
            const float4 B = s_tab[2*t+1];
            const float cw = fminf(pxr, A.y) - fmaxf(pxl, A.x);
            const float ch = fminf(pyr, A.w) - fmaxf(pyl, A.z);
            const float inter = fmaxf(cw, 0.f) * fmaxf(ch, 0.f);
            // inter/uni > 0.6  <=>  1.6*inter > 0.6*parea + 0.6*garea
            ignored = ignored || (1.6f*inter > c06 + B.x);
            if (__float_as_int(B.y) == mykey) hit = t;
        }

        const float tconf = (hit >= 0) ? 1.f : (ignored ? -1.f : 0.f);
        if (tconf != -1.f)
            acc += softplus_fast(lconf) - tconf * lconf;

        if (hit >= 0) {
            const float4 C0 = s_tab[100 + 2*hit];
            const float4 C1 = s_tab[100 + 2*hit + 1];
            const float cs = C1.x;
            acc += cs * (softplus_fast(lx) - C0.x * lx);
            acc += cs * (softplus_fast(ly) - C0.y * ly);
            const float dw = lw - C0.z;
            const float dh = lh - C0.w;
            acc += 0.5f * cs * (dw*dw + dh*dh);

            // rebuild class bitmask (rare path: only hit cells)
            unsigned long long cmask0 = 0ull, cmask1 = 0ull;
            for (int t = 0; t < TMAX; ++t) {
                const float4 B = s_tab[2*t+1];
                if (__float_as_int(B.y) == mykey) {
                    const int c = (int)B.z;
                    if (c < 64) cmask0 |= (1ull << c);
                    else        cmask1 |= (1ull << (c - 64));
                }
            }

            const float* cb = base + (size_t)5 * PLANE;
            if (ignored) {
                // zero-slice applied: all 80 classes participate
                for (int c = 0; c < NCLS; ++c) {
                    const float l = cb[(size_t)c * PLANE];
                    const bool one = (c < 64) ? ((cmask0 >> c) & 1ull)
                                              : ((cmask1 >> (c - 64)) & 1ull);
                    acc += softplus_fast(l) - (one ? l : 0.f);
                }
            } else {
                unsigned long long m0 = cmask0, m1 = cmask1;
                while (m0) {
                    const int c = __ffsll((unsigned long long)m0) - 1;
                    m0 &= (m0 - 1);
                    const float l = cb[(size_t)c * PLANE];
                    acc += softplus_fast(l) - l;
                }
                while (m1) {
                    const int c = __ffsll((unsigned long long)m1) - 1 + 64;
                    m1 &= (m1 - 1);
                    const float l = cb[(size_t)c * PLANE];
                    acc += softplus_fast(l) - l;
                }
            }
        }
    }

    // ---------- reduction: wave64 shuffle -> LDS -> one atomic per block ----------
    for (int off = 32; off > 0; off >>= 1)
        acc += __shfl_down(acc, off, 64);
    const int wave = tid >> 6;
    const int lane = tid & 63;
    if (lane == 0) s_red[wave] = acc;
    __syncthreads();
    if (tid == 0) {
        float s = s_red[0] + s_red[1] + s_red[2] + s_red[3];
        atomicAdd(out, s);
    }
}

extern "C" void kernel_launch(void* const* d_in, const int* in_sizes, int n_in,
                              void* d_out, int out_size, void* d_ws, size_t ws_size,
                              hipStream_t stream) {
    const float* inp = (const float*)d_in[0];   // (32, 255, 52, 52) f32
    const float* tgt = (const float*)d_in[1];   // (32, 250) f32
    float* out = (float*)d_out;                 // 1 f32

    yolo_zero<<<dim3(1), dim3(64), 0, stream>>>(out);

    dim3 grid((PLANE + 255) / 256, 32 * 3);     // 11 x 96
    yolo_main<<<grid, dim3(256), 0, stream>>>(inp, tgt, out);
}